// Round 7
// baseline (40706.586 us; speedup 1.0000x reference)
//
#include <hip/hip_runtime.h>

#define T_LEN 16384
#define NT 1024
#define NBLK 256
#define NTHR 64     // one wave: no barriers anywhere

typedef unsigned long long u64;
typedef unsigned int u32;
typedef __fp16 half2v __attribute__((ext_vector_type(2)));

// ws layout (bytes):
//   [0,8192)      u64 buf[2][512] — tagged delta words, parity-double-buffered
//                 word w carries cols {2w, 2w+1}: [tag32 | f16 d0 | f16 d1]
//   [8192,12288)  float a0buf[1024]   (alpha_0, f32)
//   [12288,16384) float finalA[1024]  (alpha_{T-1}, f32)
//   [16384]       float gold

__device__ __forceinline__ u64 ld_a(const u64* p) {
  return __hip_atomic_load(p, __ATOMIC_RELAXED, __HIP_MEMORY_SCOPE_AGENT);
}
__device__ __forceinline__ void st_a(u64* p, u64 v) {
  __hip_atomic_store(p, v, __ATOMIC_RELAXED, __HIP_MEMORY_SCOPE_AGENT);
}

__global__ __launch_bounds__(1024) void crf_init(const float* __restrict__ emit,
                                                 const float* __restrict__ strans,
                                                 float* __restrict__ ws) {
  int tid = threadIdx.x;
  ws[2048 + tid] = strans[tid] + emit[tid];   // a0buf
}

__global__ __launch_bounds__(1024) void crf_score(const float* __restrict__ emit,
                                                  const int* __restrict__ y,
                                                  const float* __restrict__ trans,
                                                  const float* __restrict__ strans,
                                                  const float* __restrict__ etrans,
                                                  float* __restrict__ ws) {
  int tid = threadIdx.x;
  float local = 0.f;
  for (int t = tid; t < T_LEN; t += 1024) {
    int yt = y[t];
    local += emit[t * NT + yt];
    if (t > 0) local += trans[y[t - 1] * NT + yt];
  }
  if (tid == 0) local += strans[y[0]];
  if (tid == 1023) local += etrans[y[T_LEN - 1]];
#pragma unroll
  for (int o = 32; o; o >>= 1) local += __shfl_xor(local, o);
  __shared__ float sm[16];
  if ((tid & 63) == 0) sm[tid >> 6] = local;
  __syncthreads();
  if (tid == 0) {
    float s = 0.f;
    for (int i = 0; i < 16; ++i) s += sm[i];
    ws[4096] = s;
  }
}

__global__ __launch_bounds__(NTHR, 1) void crf_scan(const float* __restrict__ emit,
                                                    const float* __restrict__ trans,
                                                    float* ws) {
  const int l = threadIdx.x;        // 0..63
  const int b = blockIdx.x;         // 0..255, owns cols 4b..4b+3
  const int colb = b * 4;

  u64* buf = (u64*)ws;              // [2][512]
  const float* a0buf = ws + 2048;
  float* finalA = ws + 3072;

  // P fragment: lane l covers j in {128*i + 2*l + h : i<8, h<2} (16 j's).
  // p[4*k + c] = exp(trans[j_k][colb+c]), k = 2*i+h.
  float p[64];
#pragma unroll
  for (int i = 0; i < 8; ++i) {
#pragma unroll
    for (int h = 0; h < 2; ++h) {
      int j = 128 * i + 2 * l + h;
      float4 t4 = *(const float4*)(trans + j * NT + colb);
      int k = 2 * i + h;
      p[4 * k + 0] = __expf(t4.x);
      p[4 * k + 1] = __expf(t4.y);
      p[4 * k + 2] = __expf(t4.z);
      p[4 * k + 3] = __expf(t4.w);
    }
  }

  // register-resident f32 reconstruction of this lane's 16 alphas
  float aRec[16];
#pragma unroll
  for (int i = 0; i < 8; ++i) {
    aRec[2 * i]     = a0buf[128 * i + 2 * l];
    aRec[2 * i + 1] = a0buf[128 * i + 2 * l + 1];
  }
  // producer's own running copy of its 4 columns (identical to what every
  // consumer reconstructs, since both advance by the same rounded f16 deltas)
  float aOwn0, aOwn1, aOwn2, aOwn3;
  {
    float4 t = *(const float4*)(a0buf + colb);
    aOwn0 = t.x; aOwn1 = t.y; aOwn2 = t.z; aOwn3 = t.w;
  }
  // initial scale: global max of alpha_0 (exact; later lagged block-local)
  float M;
  {
    float m = aRec[0];
#pragma unroll
    for (int i = 1; i < 16; ++i) m = fmaxf(m, aRec[i]);
#pragma unroll
    for (int o = 1; o < 64; o <<= 1) m = fmaxf(m, __shfl_xor(m, o));
    M = m;
  }
  float4 eC = *(const float4*)(emit + NT + colb);   // emit[1]

  for (int t = 1; t < T_LEN; ++t) {
    const u32 want = (u32)(t - 1);
    const u64* bIn = buf + ((t - 1) & 1) * 512;
    u64* bOut      = buf + (t & 1) * 512;

    // deep emit prefetch (no barrier ever forces vmcnt(0) on it)
    int tn = (t + 1 < T_LEN) ? t + 1 : t;
    float4 eN = *(const float4*)(emit + tn * NT + colb);

    if (t > 1) {
      // poll 8 self-tagged delta words (lane l owns words 64*i + l)
      u64 w[8];
      bool ok;
      do {
#pragma unroll
        for (int i = 0; i < 8; ++i) w[i] = ld_a(bIn + 64 * i + l);
        ok = true;
#pragma unroll
        for (int i = 0; i < 8; ++i) ok &= ((u32)(w[i] >> 32) == want);
      } while (!ok);
      // apply deltas to the f32 reconstruction
#pragma unroll
      for (int i = 0; i < 8; ++i) {
        half2v h = __builtin_bit_cast(half2v, (u32)w[i]);
        aRec[2 * i]     += (float)h.x;
        aRec[2 * i + 1] += (float)h.y;
      }
    }

    // GEMV from registers: 16 exp + 64 FMA; no LDS staging
    float s0 = 0.f, s1 = 0.f, s2 = 0.f, s3 = 0.f;
#pragma unroll
    for (int k = 0; k < 16; ++k) {
      float e = __expf(aRec[k] - M);
      s0 = fmaf(e, p[4 * k + 0], s0);
      s1 = fmaf(e, p[4 * k + 1], s1);
      s2 = fmaf(e, p[4 * k + 2], s2);
      s3 = fmaf(e, p[4 * k + 3], s3);
    }
    // full 64-lane butterfly: every lane ends with all 4 column sums
#pragma unroll
    for (int o = 1; o < 64; o <<= 1) {
      s0 += __shfl_xor(s0, o);
      s1 += __shfl_xor(s1, o);
      s2 += __shfl_xor(s2, o);
      s3 += __shfl_xor(s3, o);
    }

    float an0 = eC.x + M + __logf(s0);
    float an1 = eC.y + M + __logf(s1);
    float an2 = eC.z + M + __logf(s2);
    float an3 = eC.w + M + __logf(s3);

    // pack deltas (f16, RTZ) and publish two self-tagged words
    half2v pA = __builtin_amdgcn_cvt_pkrtz(an0 - aOwn0, an1 - aOwn1);
    half2v pB = __builtin_amdgcn_cvt_pkrtz(an2 - aOwn2, an3 - aOwn3);
    u32 loA = __builtin_bit_cast(u32, pA);
    u32 loB = __builtin_bit_cast(u32, pB);
    if (l == 0) {
      u64 hi = (u64)(u32)t << 32;
      st_a(bOut + 2 * b,     hi | loA);
      st_a(bOut + 2 * b + 1, hi | loB);
    }
    // advance own copy by the rounded deltas (matches consumers bitwise)
    aOwn0 += (float)pA.x; aOwn1 += (float)pA.y;
    aOwn2 += (float)pB.x; aOwn3 += (float)pB.y;

    // lagged block-local scale for next step (exp headroom is enormous)
    M = fmaxf(fmaxf(an0, an1), fmaxf(an2, an3));
    eC = eN;
  }

  // publish final alpha (f32) for crf_final; kernel boundary makes it visible
  if (l == 0) {
    float4 fa = { aOwn0, aOwn1, aOwn2, aOwn3 };
    *(float4*)(finalA + colb) = fa;
  }
}

__global__ __launch_bounds__(1024) void crf_final(const float* __restrict__ etrans,
                                                  const float* __restrict__ ws,
                                                  float* __restrict__ out) {
  int tid = threadIdx.x;
  float v = ws[3072 + tid] + etrans[tid];   // finalA
  float m = v;
#pragma unroll
  for (int o = 32; o; o >>= 1) m = fmaxf(m, __shfl_xor(m, o));
  __shared__ float sm[16];
  __shared__ float sM;
  if ((tid & 63) == 0) sm[tid >> 6] = m;
  __syncthreads();
  if (tid == 0) {
    float mm = sm[0];
    for (int i = 1; i < 16; ++i) mm = fmaxf(mm, sm[i]);
    sM = mm;
  }
  __syncthreads();
  float Mv = sM;
  float s = __expf(v - Mv);
#pragma unroll
  for (int o = 32; o; o >>= 1) s += __shfl_xor(s, o);
  __shared__ float ss[16];
  if ((tid & 63) == 0) ss[tid >> 6] = s;
  __syncthreads();
  if (tid == 0) {
    float tot = 0.f;
    for (int i = 0; i < 16; ++i) tot += ss[i];
    out[0] = Mv + __logf(tot) - ws[4096];
  }
}

extern "C" void kernel_launch(void* const* d_in, const int* in_sizes, int n_in,
                              void* d_out, int out_size, void* d_ws, size_t ws_size,
                              hipStream_t stream) {
  const float* emit = (const float*)d_in[0];
  const int* y = (const int*)d_in[1];
  const float* trans = (const float*)d_in[2];
  const float* strans = (const float*)d_in[3];
  const float* etrans = (const float*)d_in[4];
  float* ws = (float*)d_ws;
  float* out = (float*)d_out;

  crf_init<<<1, 1024, 0, stream>>>(emit, strans, ws);
  crf_score<<<1, 1024, 0, stream>>>(emit, y, trans, strans, etrans, ws);
  crf_scan<<<NBLK, NTHR, 0, stream>>>(emit, trans, ws);
  crf_final<<<1, 1024, 0, stream>>>(etrans, ws, out);
}

// Round 8
// 26997.946 us; speedup vs baseline: 1.5078x; 1.5078x over previous
//
#include <hip/hip_runtime.h>

#define T_LEN 16384
#define NT 1024
#define NBLK 256
#define NTHR 64     // one wave: no barriers anywhere

typedef unsigned long long u64;
typedef unsigned int u32;

// ws layout:
//   float ws[0..1024)    a0buf (alpha_0)
//   float ws[1024..2048) finalA (alpha_{T-1})
//   float ws[2048]       gold score
//   byte 16384: u64 buf[R][2][1024] — R replicas × parity × tagged words
//   tagged word = (step_tag << 32) | f32_bits; poison 0xAAAAAAAA never matches

__device__ __forceinline__ u64 ld_a(const u64* p) {
  return __hip_atomic_load(p, __ATOMIC_RELAXED, __HIP_MEMORY_SCOPE_AGENT);
}
__device__ __forceinline__ void st_a(u64* p, u64 v) {
  __hip_atomic_store(p, v, __ATOMIC_RELAXED, __HIP_MEMORY_SCOPE_AGENT);
}
__device__ __forceinline__ u64 pack(u32 tag, float v) {
  return ((u64)tag << 32) | (u64)__float_as_uint(v);
}

__global__ __launch_bounds__(1024) void crf_init(const float* __restrict__ emit,
                                                 const float* __restrict__ strans,
                                                 float* __restrict__ ws) {
  int tid = threadIdx.x;
  ws[tid] = strans[tid] + emit[tid];   // a0buf
}

__global__ __launch_bounds__(1024) void crf_score(const float* __restrict__ emit,
                                                  const int* __restrict__ y,
                                                  const float* __restrict__ trans,
                                                  const float* __restrict__ strans,
                                                  const float* __restrict__ etrans,
                                                  float* __restrict__ ws) {
  int tid = threadIdx.x;
  float local = 0.f;
  for (int t = tid; t < T_LEN; t += 1024) {
    int yt = y[t];
    local += emit[t * NT + yt];
    if (t > 0) local += trans[y[t - 1] * NT + yt];
  }
  if (tid == 0) local += strans[y[0]];
  if (tid == 1023) local += etrans[y[T_LEN - 1]];
#pragma unroll
  for (int o = 32; o; o >>= 1) local += __shfl_xor(local, o);
  __shared__ float sm[16];
  if ((tid & 63) == 0) sm[tid >> 6] = local;
  __syncthreads();
  if (tid == 0) {
    float s = 0.f;
    for (int i = 0; i < 16; ++i) s += sm[i];
    ws[2048] = s;
  }
}

__global__ __launch_bounds__(NTHR, 1) void crf_scan(const float* __restrict__ emit,
                                                    const float* __restrict__ trans,
                                                    float* ws, u64* buf, int Rm1) {
  const int l = threadIdx.x;        // 0..63
  const int b = blockIdx.x;         // owns cols 4b..4b+3
  const int colb = b * 4;

  // P fragment: lane l owns j in {64i + l}; p[4i+c] = exp(trans[j][colb+c])
  float p[64];
#pragma unroll
  for (int i = 0; i < 16; ++i) {
    float4 t4 = *(const float4*)(trans + (64 * i + l) * NT + colb);
    p[4 * i + 0] = __expf(t4.x);
    p[4 * i + 1] = __expf(t4.y);
    p[4 * i + 2] = __expf(t4.z);
    p[4 * i + 3] = __expf(t4.w);
  }

  // alpha_0 for this lane's 16 j's
  float a0r[16];
#pragma unroll
  for (int i = 0; i < 16; ++i) a0r[i] = ws[64 * i + l];

  // initial scale: exact global max of alpha_0
  float M;
  {
    float m = a0r[0];
#pragma unroll
    for (int i = 1; i < 16; ++i) m = fmaxf(m, a0r[i]);
#pragma unroll
    for (int o = 1; o < 64; o <<= 1) m = fmaxf(m, __shfl_xor(m, o));
    M = m;
  }

  const u64* repIn = buf + (u64)(b & Rm1) * 2048;   // this block's poll replica
  float4 eC = *(const float4*)(emit + NT + colb);   // emit[1]
  float an = 0.f;

  for (int t = 1; t < T_LEN; ++t) {
    const u32 want = (u32)(t - 1);

    // deep emit prefetch for t+1 (no barrier ever drains it)
    int tn = (t + 1 < T_LEN) ? t + 1 : t;
    float4 eN = *(const float4*)(emit + tn * NT + colb);

    float ev[16];
    if (t == 1) {
#pragma unroll
      for (int i = 0; i < 16; ++i) ev[i] = a0r[i];
    } else {
      const u64* bIn = repIn + (u64)((t - 1) & 1) * 1024;
      u64 w[16];
      bool ok;
      do {
#pragma unroll
        for (int i = 0; i < 16; ++i) w[i] = ld_a(bIn + i * 64 + l);
        ok = true;
#pragma unroll
        for (int i = 0; i < 16; ++i) ok &= ((u32)(w[i] >> 32) == want);
      } while (!ok);
#pragma unroll
      for (int i = 0; i < 16; ++i) ev[i] = __uint_as_float((u32)w[i]);
    }

    // register GEMV: 16 exp + 64 FMA
    float s0 = 0.f, s1 = 0.f, s2 = 0.f, s3 = 0.f;
#pragma unroll
    for (int i = 0; i < 16; ++i) {
      float e = __expf(ev[i] - M);
      s0 = fmaf(e, p[4 * i + 0], s0);
      s1 = fmaf(e, p[4 * i + 1], s1);
      s2 = fmaf(e, p[4 * i + 2], s2);
      s3 = fmaf(e, p[4 * i + 3], s3);
    }

    // value-migrating reduction: col bit0->lane bit0, col bit1->lane bit1,
    // then accumulate over lane bits 2..5. Every lane ends with the FULL
    // 1024-j sum for col = l&3.
    float aK = (l & 1) ? s1 : s0, aSnd = (l & 1) ? s0 : s1;
    float t0 = aK + __shfl_xor(aSnd, 1);
    float bK = (l & 1) ? s3 : s2, bSnd = (l & 1) ? s2 : s3;
    float t1 = bK + __shfl_xor(bSnd, 1);
    float qK = (l & 2) ? t1 : t0, qSnd = (l & 2) ? t0 : t1;
    float q = qK + __shfl_xor(qSnd, 2);
    q += __shfl_xor(q, 4);
    q += __shfl_xor(q, 8);
    q += __shfl_xor(q, 16);
    q += __shfl_xor(q, 32);

    // emit component for this lane's column
    float e01 = (l & 1) ? eC.y : eC.x;
    float e23 = (l & 1) ? eC.w : eC.z;
    float eSel = (l & 2) ? e23 : e01;

    an = eSel + M + __logf(q);

    // publish to ALL replicas in one instruction: lane l<4R -> replica l>>2,
    // col l&3. Each replica receives one contiguous full 32B sector.
    if (l < 4 * (Rm1 + 1)) {
      u64* dst = buf + (u64)(l >> 2) * 2048 + (u64)(t & 1) * 1024 + 4 * b + (l & 3);
      st_a(dst, pack((u32)t, an));
    }

    // lagged block-local scale for next step (2 shuffles, all lanes valid)
    float m2 = fmaxf(an, __shfl_xor(an, 1));
    M = fmaxf(m2, __shfl_xor(m2, 2));
    eC = eN;
  }

  // publish final alpha (f32) for crf_final
  if (l < 4) ws[1024 + colb + l] = an;
}

__global__ __launch_bounds__(1024) void crf_final(const float* __restrict__ etrans,
                                                  const float* __restrict__ ws,
                                                  float* __restrict__ out) {
  int tid = threadIdx.x;
  float v = ws[1024 + tid] + etrans[tid];   // finalA
  float m = v;
#pragma unroll
  for (int o = 32; o; o >>= 1) m = fmaxf(m, __shfl_xor(m, o));
  __shared__ float sm[16];
  __shared__ float sM;
  if ((tid & 63) == 0) sm[tid >> 6] = m;
  __syncthreads();
  if (tid == 0) {
    float mm = sm[0];
    for (int i = 1; i < 16; ++i) mm = fmaxf(mm, sm[i]);
    sM = mm;
  }
  __syncthreads();
  float Mv = sM;
  float s = __expf(v - Mv);
#pragma unroll
  for (int o = 32; o; o >>= 1) s += __shfl_xor(s, o);
  __shared__ float ss[16];
  if ((tid & 63) == 0) ss[tid >> 6] = s;
  __syncthreads();
  if (tid == 0) {
    float tot = 0.f;
    for (int i = 0; i < 16; ++i) tot += ss[i];
    out[0] = Mv + __logf(tot) - ws[2048];
  }
}

extern "C" void kernel_launch(void* const* d_in, const int* in_sizes, int n_in,
                              void* d_out, int out_size, void* d_ws, size_t ws_size,
                              hipStream_t stream) {
  const float* emit = (const float*)d_in[0];
  const int* y = (const int*)d_in[1];
  const float* trans = (const float*)d_in[2];
  const float* strans = (const float*)d_in[3];
  const float* etrans = (const float*)d_in[4];
  float* ws = (float*)d_ws;
  u64* buf = (u64*)((char*)d_ws + 16384);
  float* out = (float*)d_out;

  // replicas: largest pow2 R<=8 with 16384 + R*16KiB <= ws_size
  size_t avail = ws_size > 16384 ? ws_size - 16384 : 0;
  int R = 1;
  while (R < 8 && (size_t)(2 * R) * 16384ull <= avail) R <<= 1;

  crf_init<<<1, 1024, 0, stream>>>(emit, strans, ws);
  crf_score<<<1, 1024, 0, stream>>>(emit, y, trans, strans, etrans, ws);
  crf_scan<<<NBLK, NTHR, 0, stream>>>(emit, trans, ws, buf, R - 1);
  crf_final<<<1, 1024, 0, stream>>>(etrans, ws, out);
}